// Round 2
// baseline (462.915 us; speedup 1.0000x reference)
//
#include <hip/hip_runtime.h>

// Problem constants (reference: B=4096, CELL=400, K=10, T=256, V=80)
#define BB   4096
#define CELL 400
#define KK   10
#define TT   256
#define VV   80

// ---------------------------------------------------------------------------
// Kernel A: phi[B,T] + kappa out. One wave per batch row, 4 rows per block.
// No barriers; W reads coalesced (lane-contiguous); butterfly reductions.
// ---------------------------------------------------------------------------
__global__ __launch_bounds__(256) void phi_kernel(
    const float* __restrict__ x,         // [B, CELL]
    const float* __restrict__ kappa_old, // [B, K]
    const float* __restrict__ W,         // [3K, CELL]
    const float* __restrict__ bias,      // [3K]
    float* __restrict__ out,             // kappa at offset B*V
    float* __restrict__ phi)             // [B, T] workspace
{
    const int tid  = threadIdx.x;
    const int lane = tid & 63;
    const int wav  = tid >> 6;
    const int b    = blockIdx.x * 4 + wav;

    // x row into registers, coalesced: i = lane + 64c
    float xr[7];
    const float* xrow = x + (size_t)b * CELL;
    #pragma unroll
    for (int c = 0; c < 7; ++c) {
        const int i = lane + 64 * c;
        xr[c] = (i < CELL) ? xrow[i] : 0.f;
    }

    float acc0 = 0.f, acc1 = 0.f, acc2 = 0.f, acc3 = 0.f; // phi for t=lane+64q

    #pragma unroll
    for (int k = 0; k < KK; ++k) {
        float pa = 0.f, pb = 0.f, pc = 0.f;
        const float* wa = W + (size_t)k * CELL;
        const float* wb = W + (size_t)(k + KK) * CELL;
        const float* wc = W + (size_t)(k + 2 * KK) * CELL;
        #pragma unroll
        for (int c = 0; c < 7; ++c) {
            const int i = lane + 64 * c;
            if (i < CELL) {
                pa += xr[c] * wa[i];   // coalesced: 64 consecutive floats/wave
                pb += xr[c] * wb[i];
                pc += xr[c] * wc[i];
            }
        }
        // butterfly reduce: every lane ends with the full dot
        #pragma unroll
        for (int m = 32; m >= 1; m >>= 1) {
            pa += __shfl_xor(pa, m, 64);
            pb += __shfl_xor(pb, m, 64);
            pc += __shfl_xor(pc, m, 64);
        }
        const float a  = __expf(pa + bias[k]);
        const float be = __expf(pb + bias[k + KK]);
        const float ka = kappa_old[(size_t)b * KK + k] + __expf(pc + bias[k + 2 * KK]);
        if (lane == k) out[(size_t)BB * VV + (size_t)b * KK + k] = ka;

        // accumulate this component into phi for this lane's 4 t-positions
        {
            float d0 = ka - (float)(lane);
            float d1 = ka - (float)(lane + 64);
            float d2 = ka - (float)(lane + 128);
            float d3 = ka - (float)(lane + 192);
            acc0 += a * __expf(-be * d0 * d0);
            acc1 += a * __expf(-be * d1 * d1);
            acc2 += a * __expf(-be * d2 * d2);
            acc3 += a * __expf(-be * d3 * d3);
        }
    }

    float* ph = phi + (size_t)b * TT;
    ph[lane]       = acc0;
    ph[lane + 64]  = acc1;
    ph[lane + 128] = acc2;
    ph[lane + 192] = acc3;
}

// ---------------------------------------------------------------------------
// Kernel B: weight[b,v] = sum_t phi[b,t] * onehots[b,t,v]. Pure HBM stream.
// 320 threads/block, one block per row; tid = g*20+vv so flat float4 index
// tid + 320*it is fully contiguous per iteration (perfect coalescing).
// ---------------------------------------------------------------------------
__global__ __launch_bounds__(320) void einsum_kernel(
    const float* __restrict__ onehots,   // [B, T, V]
    const float* __restrict__ phi,       // [B, T]
    float* __restrict__ out)             // weight at offset 0
{
    __shared__ float  phi_lds[TT];
    __shared__ float4 part_lds[320];

    const int b   = blockIdx.x;
    const int tid = threadIdx.x;

    // stage phi row (short barrier; only 64 float4 loads outstanding)
    if (tid < 64) {
        ((float4*)phi_lds)[tid] = ((const float4*)(phi + (size_t)b * TT))[tid];
    }
    __syncthreads();

    const float4* oh4 = (const float4*)(onehots + (size_t)b * TT * VV);
    const int g = tid / 20;  // 0..15
    float4 acc = {0.f, 0.f, 0.f, 0.f};
    #pragma unroll
    for (int it = 0; it < 16; ++it) {
        const float  ph = phi_lds[g + 16 * it];   // broadcast read
        const float4 o  = oh4[tid + 320 * it];    // contiguous 5120 B/iter/block
        acc.x += ph * o.x;
        acc.y += ph * o.y;
        acc.z += ph * o.z;
        acc.w += ph * o.w;
    }
    part_lds[tid] = acc;
    __syncthreads();

    if (tid < 20) {
        float4 s = {0.f, 0.f, 0.f, 0.f};
        #pragma unroll
        for (int gg = 0; gg < 16; ++gg) {
            const float4 p = part_lds[gg * 20 + tid];
            s.x += p.x; s.y += p.y; s.z += p.z; s.w += p.w;
        }
        ((float4*)(out + (size_t)b * VV))[tid] = s;
    }
}

extern "C" void kernel_launch(void* const* d_in, const int* in_sizes, int n_in,
                              void* d_out, int out_size, void* d_ws, size_t ws_size,
                              hipStream_t stream) {
    const float* x         = (const float*)d_in[0];
    const float* kappa_old = (const float*)d_in[1];
    const float* onehots   = (const float*)d_in[2];
    const float* W         = (const float*)d_in[3];
    const float* bias      = (const float*)d_in[4];
    float* out = (float*)d_out;
    float* phi = (float*)d_ws;           // 4096*256*4 = 4 MB scratch

    phi_kernel<<<BB / 4, 256, 0, stream>>>(x, kappa_old, W, bias, out, phi);
    einsum_kernel<<<BB, 320, 0, stream>>>(onehots, phi, out);
}

// Round 3
// 458.967 us; speedup vs baseline: 1.0086x; 1.0086x over previous
//
#include <hip/hip_runtime.h>

// Problem constants (reference: B=4096, CELL=400, K=10, T=256, V=80)
#define BB   4096
#define CELL 400
#define KK   10
#define TT   256
#define VV   80

// Fused kernel: one block (320 threads = 5 waves) per batch row.
// Phase order: prefetch onehots -> coalesced 30x400 GEMM -> alpha/beta/kappa
// -> phi -> register-resident einsum accumulate -> LDS reduce -> store.
__global__ __launch_bounds__(320) void window_fused(
    const float* __restrict__ x,         // [B, CELL]
    const float* __restrict__ kappa_old, // [B, K]
    const float* __restrict__ onehots,   // [B, T, V]
    const float* __restrict__ W,         // [3K, CELL]
    const float* __restrict__ bias,      // [3K]
    float* __restrict__ out)             // [B*V weight][B*K kappa]
{
    __shared__ float  p_lds[30];
    __shared__ float  alpha_lds[KK], beta_lds[KK], kappa_lds[KK];
    __shared__ float  phi_lds[TT];
    __shared__ float4 part_lds[320];

    const int b    = blockIdx.x;
    const int tid  = threadIdx.x;
    const int lane = tid & 63;
    const int wav  = tid >> 6;        // 0..4

    // ---- Prefetch: this thread's 16 float4 of the onehots row (80 KB/block,
    // fully contiguous per unrolled iteration). Issued first so HBM is busy
    // while the GEMM/phi phases run under the load shadow. ----
    const float4* oh4 = (const float4*)(onehots + (size_t)b * TT * VV);
    float4 o[16];
    #pragma unroll
    for (int it = 0; it < 16; ++it) o[it] = oh4[tid + 320 * it];

    float ko = 0.f;
    if (tid < KK) ko = kappa_old[(size_t)b * KK + tid];

    // ---- Phase A: params = x @ W^T + b. 5 waves x 6 rows, coalesced. ----
    float xr[7];
    const float* xrow = x + (size_t)b * CELL;
    #pragma unroll
    for (int c = 0; c < 7; ++c) {
        const int i = lane + 64 * c;
        xr[c] = (i < CELL) ? xrow[i] : 0.f;
    }
    #pragma unroll
    for (int r = 0; r < 6; ++r) {
        const int j = wav * 6 + r;    // 0..29
        const float* wrow = W + (size_t)j * CELL;
        float s = 0.f;
        #pragma unroll
        for (int c = 0; c < 7; ++c) {
            const int i = lane + 64 * c;
            if (i < CELL) s += xr[c] * wrow[i];   // 64 consecutive floats/wave
        }
        #pragma unroll
        for (int m = 32; m >= 1; m >>= 1) s += __shfl_xor(s, m, 64);
        if (lane == 0) p_lds[j] = s + bias[j];
    }
    __syncthreads();

    // ---- Phase B: alpha/beta/kappa; write kappa output ----
    if (tid < KK) {
        const float a  = __expf(p_lds[tid]);
        const float be = __expf(p_lds[KK + tid]);
        const float ka = ko + __expf(p_lds[2 * KK + tid]);
        alpha_lds[tid] = a;
        beta_lds[tid]  = be;
        kappa_lds[tid] = ka;
        out[(size_t)BB * VV + (size_t)b * KK + tid] = ka;
    }
    __syncthreads();

    // ---- Phase C: phi[t] = sum_k alpha_k * exp(-beta_k * (kappa_k - t)^2) ----
    if (tid < TT) {
        const float u = (float)tid;
        float s = 0.f;
        #pragma unroll
        for (int k = 0; k < KK; ++k) {
            const float d = kappa_lds[k] - u;
            s += alpha_lds[k] * __expf(-beta_lds[k] * d * d);
        }
        phi_lds[tid] = s;
    }
    __syncthreads();

    // ---- Phase D: accumulate weight partials from prefetched registers ----
    {
        const int g = tid / 20;       // 0..15
        float4 acc = {0.f, 0.f, 0.f, 0.f};
        #pragma unroll
        for (int it = 0; it < 16; ++it) {
            const float ph = phi_lds[g + 16 * it];
            acc.x += ph * o[it].x;
            acc.y += ph * o[it].y;
            acc.z += ph * o[it].z;
            acc.w += ph * o[it].w;
        }
        part_lds[tid] = acc;
    }
    __syncthreads();

    // ---- Phase E: reduce 16 partials per v-float4, store weight ----
    if (tid < 20) {
        float4 s = {0.f, 0.f, 0.f, 0.f};
        #pragma unroll
        for (int g = 0; g < 16; ++g) {
            const float4 p = part_lds[g * 20 + tid];
            s.x += p.x; s.y += p.y; s.z += p.z; s.w += p.w;
        }
        ((float4*)(out + (size_t)b * VV))[tid] = s;
    }
}

extern "C" void kernel_launch(void* const* d_in, const int* in_sizes, int n_in,
                              void* d_out, int out_size, void* d_ws, size_t ws_size,
                              hipStream_t stream) {
    const float* x         = (const float*)d_in[0];
    const float* kappa_old = (const float*)d_in[1];
    const float* onehots   = (const float*)d_in[2];
    const float* W         = (const float*)d_in[3];
    const float* bias      = (const float*)d_in[4];
    float* out = (float*)d_out;

    window_fused<<<BB, 320, 0, stream>>>(x, kappa_old, onehots, W, bias, out);
}

// Round 4
// 455.717 us; speedup vs baseline: 1.0158x; 1.0071x over previous
//
#include <hip/hip_runtime.h>

// Problem constants (reference: B=4096, CELL=400, K=10, T=256, V=80)
#define BB   4096
#define CELL 400
#define KK   10
#define TT   256
#define VV   80

// Fused kernel: one block (320 threads = 5 waves) per batch row.
// R1 structure (inline einsum loads — TLP hides latency, low VGPR) with the
// coalesced GEMM from R3 (5 waves x 6 W-rows, lane-contiguous reads).
__global__ __launch_bounds__(320) void window_fused(
    const float* __restrict__ x,         // [B, CELL]
    const float* __restrict__ kappa_old, // [B, K]
    const float* __restrict__ onehots,   // [B, T, V]
    const float* __restrict__ W,         // [3K, CELL]
    const float* __restrict__ bias,      // [3K]
    float* __restrict__ out)             // [B*V weight][B*K kappa]
{
    __shared__ float  p_lds[30];
    __shared__ float  alpha_lds[KK], beta_lds[KK], kappa_lds[KK];
    __shared__ float  phi_lds[TT];
    __shared__ float4 part_lds[320];

    const int b    = blockIdx.x;
    const int tid  = threadIdx.x;
    const int lane = tid & 63;
    const int wav  = tid >> 6;        // 0..4

    // ---- Phase A: params = x @ W^T + b. Coalesced: each wave does 6 rows,
    // lanes read consecutive floats of W and x. ----
    float xr[7];
    const float* xrow = x + (size_t)b * CELL;
    #pragma unroll
    for (int c = 0; c < 7; ++c) {
        const int i = lane + 64 * c;
        xr[c] = (i < CELL) ? xrow[i] : 0.f;
    }
    float ko = 0.f;
    if (tid < KK) ko = kappa_old[(size_t)b * KK + tid];

    #pragma unroll
    for (int r = 0; r < 6; ++r) {
        const int j = wav * 6 + r;    // 0..29
        const float* wrow = W + (size_t)j * CELL;
        float s = 0.f;
        #pragma unroll
        for (int c = 0; c < 7; ++c) {
            const int i = lane + 64 * c;
            if (i < CELL) s += xr[c] * wrow[i];   // 64 consecutive floats/wave
        }
        #pragma unroll
        for (int m = 32; m >= 1; m >>= 1) s += __shfl_xor(s, m, 64);
        if (lane == 0) p_lds[j] = s + bias[j];
    }
    __syncthreads();

    // ---- Phase B: alpha/beta/kappa; write kappa output ----
    if (tid < KK) {
        const float a  = __expf(p_lds[tid]);
        const float be = __expf(p_lds[KK + tid]);
        const float ka = ko + __expf(p_lds[2 * KK + tid]);
        alpha_lds[tid] = a;
        beta_lds[tid]  = be;
        kappa_lds[tid] = ka;
        out[(size_t)BB * VV + (size_t)b * KK + tid] = ka;
    }
    __syncthreads();

    // ---- Phase C: phi[t] = sum_k alpha_k * exp(-beta_k * (kappa_k - t)^2) ----
    if (tid < TT) {
        const float u = (float)tid;
        float s = 0.f;
        #pragma unroll
        for (int k = 0; k < KK; ++k) {
            const float d = kappa_lds[k] - u;
            s += alpha_lds[k] * __expf(-beta_lds[k] * d * d);
        }
        phi_lds[tid] = s;
    }
    __syncthreads();

    // ---- Phase D: einsum partials, loads inline (latency hidden by TLP).
    // tid = g*20+vv; flat float4 index tid + 320*it is fully contiguous per
    // iteration: 5120 B per block per it, perfect coalescing. ----
    {
        const float4* oh4 = (const float4*)(onehots + (size_t)b * TT * VV);
        const int g = tid / 20;  // 0..15
        float4 acc = {0.f, 0.f, 0.f, 0.f};
        #pragma unroll
        for (int it = 0; it < 16; ++it) {
            const float  ph = phi_lds[g + 16 * it];
            const float4 o  = oh4[tid + 320 * it];
            acc.x += ph * o.x;
            acc.y += ph * o.y;
            acc.z += ph * o.z;
            acc.w += ph * o.w;
        }
        part_lds[tid] = acc;
    }
    __syncthreads();

    // ---- Phase E: reduce 16 partials per v-float4, store weight ----
    if (tid < 20) {
        float4 s = {0.f, 0.f, 0.f, 0.f};
        #pragma unroll
        for (int g = 0; g < 16; ++g) {
            const float4 p = part_lds[g * 20 + tid];
            s.x += p.x; s.y += p.y; s.z += p.z; s.w += p.w;
        }
        ((float4*)(out + (size_t)b * VV))[tid] = s;
    }
}

extern "C" void kernel_launch(void* const* d_in, const int* in_sizes, int n_in,
                              void* d_out, int out_size, void* d_ws, size_t ws_size,
                              hipStream_t stream) {
    const float* x         = (const float*)d_in[0];
    const float* kappa_old = (const float*)d_in[1];
    const float* onehots   = (const float*)d_in[2];
    const float* W         = (const float*)d_in[3];
    const float* bias      = (const float*)d_in[4];
    float* out = (float*)d_out;

    window_fused<<<BB, 320, 0, stream>>>(x, kappa_old, onehots, W, bias, out);
}